// Round 2
// baseline (845.683 us; speedup 1.0000x reference)
//
#include <hip/hip_runtime.h>
#include <hip/hip_bf16.h>
#include <math.h>

#define NNODE 20000
#define NEDGE 160000
#define IN_DIMV 256
#define HIDV 128
#define H4V 512 /* HEADS*HID */

__device__ __forceinline__ float bf2f(unsigned short u) {
    union { unsigned int i; float f; } x; x.i = ((unsigned int)u) << 16; return x.f;
}
__device__ __forceinline__ unsigned short f2bf(float f) {
    union { float f; unsigned int i; } x; x.f = f;
    unsigned int r = x.i + 0x7fffu + ((x.i >> 16) & 1u);
    return (unsigned short)(r >> 16);
}
__device__ __forceinline__ float cvtIn(float v) { return v; }
__device__ __forceinline__ float cvtIn(unsigned short v) { return bf2f(v); }
__device__ __forceinline__ void cvtStore(float* p, float v) { *p = v; }
__device__ __forceinline__ void cvtStore(unsigned short* p, float v) { *p = f2bf(v); }

__device__ __forceinline__ void unpack8(uint4 p, float* f) {
    f[0] = bf2f((unsigned short)(p.x & 0xffff)); f[1] = bf2f((unsigned short)(p.x >> 16));
    f[2] = bf2f((unsigned short)(p.y & 0xffff)); f[3] = bf2f((unsigned short)(p.y >> 16));
    f[4] = bf2f((unsigned short)(p.z & 0xffff)); f[5] = bf2f((unsigned short)(p.z >> 16));
    f[6] = bf2f((unsigned short)(p.w & 0xffff)); f[7] = bf2f((unsigned short)(p.w >> 16));
}

// ---------------- dtype detection ----------------
// Reads first 1024 ushorts of x. If x is f32, the low halves of each float
// have random bits in the bf16 exponent field -> ~42% "insane". If x is bf16
// (values ~N(0,1)), exponent is always in [110,129] -> ~0% insane.
// flag: 0 = bf16 inputs, 1 = f32 inputs.
__global__ void detect_kernel(const unsigned short* __restrict__ x, int* __restrict__ flag) {
    __shared__ int cnt;
    if (threadIdx.x == 0) cnt = 0;
    __syncthreads();
    int insane = 0;
    for (int i = threadIdx.x; i < 1024; i += 256) {
        unsigned short u = x[i];
        int e = (u >> 7) & 0xff;
        bool sane = ((u & 0x7fff) == 0) || (e >= 100 && e <= 140);
        if (!sane) insane++;
    }
    atomicAdd(&cnt, insane);
    __syncthreads();
    if (threadIdx.x == 0) *flag = (cnt > 100) ? 1 : 0;
}

// ---------------- GEMM: C[M,Nc] = act(A[M,K] @ W[K,Nc] + bias) ----------------
// 64x64 tile, BK=32, 256 threads, 4x4 microtile. Dual-dispatched on dtype flag.
template <typename AT, typename WT, typename OutT, bool RELU>
__global__ __launch_bounds__(256) void gemm_bias(
    const AT* __restrict__ A, const WT* __restrict__ W,
    const WT* __restrict__ Bv, OutT* __restrict__ C,
    int M, int K, int Nc, const int* __restrict__ flagp, int want)
{
    if (*flagp != want) return;
    __shared__ float As[64][33];
    __shared__ float Ws[32][65];
    int tid = threadIdx.x;
    int bm = blockIdx.x * 64;
    int bn = blockIdx.y * 64;
    int tx = tid & 15, ty = tid >> 4;
    float acc[4][4] = {{0.f}};

    for (int k0 = 0; k0 < K; k0 += 32) {
#pragma unroll
        for (int i = 0; i < 8; i++) {
            int idx = tid + i * 256;
            int r = idx >> 5, c = idx & 31;
            int gr = bm + r;
            As[r][c] = (gr < M) ? cvtIn(A[(size_t)gr * K + k0 + c]) : 0.f;
        }
#pragma unroll
        for (int i = 0; i < 8; i++) {
            int idx = tid + i * 256;
            int r = idx >> 6, c = idx & 63;
            Ws[r][c] = cvtIn(W[(size_t)(k0 + r) * Nc + bn + c]);
        }
        __syncthreads();
#pragma unroll
        for (int kk = 0; kk < 32; kk++) {
            float av[4], bv[4];
#pragma unroll
            for (int i = 0; i < 4; i++) av[i] = As[ty * 4 + i][kk];
#pragma unroll
            for (int j = 0; j < 4; j++) bv[j] = Ws[kk][tx * 4 + j];
#pragma unroll
            for (int i = 0; i < 4; i++)
#pragma unroll
                for (int j = 0; j < 4; j++) acc[i][j] += av[i] * bv[j];
        }
        __syncthreads();
    }
#pragma unroll
    for (int i = 0; i < 4; i++) {
        int gr = bm + ty * 4 + i;
        if (gr >= M) continue;
#pragma unroll
        for (int j = 0; j < 4; j++) {
            int gc = bn + tx * 4 + j;
            float v = acc[i][j] + cvtIn(Bv[gc]);
            if (RELU) v = fmaxf(v, 0.f);
            cvtStore(&C[(size_t)gr * Nc + gc], v);
        }
    }
}

// ---------------- CSR build ----------------
__global__ void hist_kernel(const int* __restrict__ ei, int* __restrict__ counts) {
    int e = blockIdx.x * blockDim.x + threadIdx.x;
    if (e < NEDGE) atomicAdd(&counts[ei[NEDGE + e]], 1);
}

__global__ __launch_bounds__(1024) void scan_kernel(int* __restrict__ cursor,
                                                    int* __restrict__ rowptr) {
    __shared__ int part[1024];
    int tid = threadIdx.x;
    const int CH = 20; // 1024*20 = 20480 >= 20000
    int base = tid * CH;
    int loc[CH];
    int s = 0;
#pragma unroll
    for (int j = 0; j < CH; j++) {
        int idx = base + j;
        int c = (idx < NNODE) ? cursor[idx] : 0;
        loc[j] = s;
        s += c;
    }
    part[tid] = s;
    __syncthreads();
    for (int off = 1; off < 1024; off <<= 1) {
        int t = (tid >= off) ? part[tid - off] : 0;
        __syncthreads();
        part[tid] += t;
        __syncthreads();
    }
    int offs = part[tid] - s; // exclusive prefix
#pragma unroll
    for (int j = 0; j < CH; j++) {
        int idx = base + j;
        if (idx < NNODE) {
            int rv = offs + loc[j];
            rowptr[idx] = rv;
            cursor[idx] = rv;
        }
    }
    if (tid == 0) rowptr[NNODE] = NEDGE;
}

__global__ void scatter_kernel(const int* __restrict__ ei, int* __restrict__ cursor,
                               int* __restrict__ colsrc) {
    int e = blockIdx.x * blockDim.x + threadIdx.x;
    if (e < NEDGE) {
        int d = ei[NEDGE + e];
        int p = atomicAdd(&cursor[d], 1);
        colsrc[p] = ei[e];
    }
}

// ---------------- Attention: wave per dst node (internal buffers only) ----------------
__global__ __launch_bounds__(256) void attn_kernel(
    const unsigned short* __restrict__ qb, const unsigned short* __restrict__ kb,
    const unsigned short* __restrict__ vb, const int* __restrict__ rowptr,
    const int* __restrict__ colsrc, float* __restrict__ scoreb,
    const float* __restrict__ hprev, float* __restrict__ pre)
{
    int lane = threadIdx.x & 63;
    int wid = threadIdx.x >> 6;
    int i = blockIdx.x * 4 + wid;
    if (i >= NNODE) return;
    int rs = rowptr[i], re = rowptr[i + 1];
    int hg = lane >> 4;

    float qr[8];
    {
        uint4 p = *(const uint4*)(qb + (size_t)i * H4V + lane * 8);
        unpack8(p, qr);
#pragma unroll
        for (int j = 0; j < 8; j++) qr[j] *= 0.0883883476483184f; // 1/sqrt(128)
    }

    float m = -INFINITY, l = 0.f;
    for (int j = rs; j < re; j++) {
        int src = colsrc[j];
        float kf[8];
        uint4 p = *(const uint4*)(kb + (size_t)src * H4V + lane * 8);
        unpack8(p, kf);
        float d = qr[0] * kf[0] + qr[1] * kf[1] + qr[2] * kf[2] + qr[3] * kf[3] +
                  qr[4] * kf[4] + qr[5] * kf[5] + qr[6] * kf[6] + qr[7] * kf[7];
        d += __shfl_xor(d, 8);
        d += __shfl_xor(d, 4);
        d += __shfl_xor(d, 2);
        d += __shfl_xor(d, 1);
        if ((lane & 15) == 0) scoreb[(size_t)j * 4 + hg] = d;
        float mn = fmaxf(m, d);
        l = l * __expf(m - mn) + __expf(d - mn);
        m = mn;
    }
    float linv = 1.f / (l + 1e-16f);

    float acc[8] = {0.f, 0.f, 0.f, 0.f, 0.f, 0.f, 0.f, 0.f};
    for (int j = rs; j < re; j++) {
        int src = colsrc[j];
        float cf = __expf(scoreb[(size_t)j * 4 + hg] - m) * linv;
        float vf[8];
        uint4 p = *(const uint4*)(vb + (size_t)src * H4V + lane * 8);
        unpack8(p, vf);
#pragma unroll
        for (int c = 0; c < 8; c++) acc[c] += cf * vf[c];
    }
#pragma unroll
    for (int c = 0; c < 8; c++) {
        acc[c] += __shfl_xor(acc[c], 16);
        acc[c] += __shfl_xor(acc[c], 32);
    }
    if (lane < 16) {
        size_t base = (size_t)i * HIDV + lane * 8;
#pragma unroll
        for (int c = 0; c < 8; c++)
            pre[base + c] = acc[c] * 0.25f + pre[base + c] + hprev[base + c];
    }
}

// ---------------- LayerNorm: wave per node. Dual-dispatched (g/b/final out are external). ----------------
template <typename T>
__global__ __launch_bounds__(256) void ln_kernel(
    const float* __restrict__ pre, const T* __restrict__ g,
    const T* __restrict__ b, float* __restrict__ hout,
    T* __restrict__ extout, const int* __restrict__ flagp, int want)
{
    if (*flagp != want) return;
    int lane = threadIdx.x & 63;
    int wid = threadIdx.x >> 6;
    int i = blockIdx.x * 4 + wid;
    if (i >= NNODE) return;
    float2 xv = ((const float2*)(pre + (size_t)i * HIDV))[lane];
    float s = xv.x + xv.y;
#pragma unroll
    for (int o = 1; o < 64; o <<= 1) s += __shfl_xor(s, o);
    float mu = s * (1.f / 128.f);
    float dx0 = xv.x - mu, dx1 = xv.y - mu;
    float vs = dx0 * dx0 + dx1 * dx1;
#pragma unroll
    for (int o = 1; o < 64; o <<= 1) vs += __shfl_xor(vs, o);
    float rstd = rsqrtf(vs * (1.f / 128.f) + 1e-5f);
    int c0 = lane * 2;
    float y0 = dx0 * rstd * cvtIn(g[c0]) + cvtIn(b[c0]);
    float y1 = dx1 * rstd * cvtIn(g[c0 + 1]) + cvtIn(b[c0 + 1]);
    hout[(size_t)i * HIDV + c0] = y0;
    hout[(size_t)i * HIDV + c0 + 1] = y1;
    if (extout) {
        cvtStore(&extout[(size_t)i * HIDV + c0], y0);
        cvtStore(&extout[(size_t)i * HIDV + c0 + 1], y1);
    }
}

extern "C" void kernel_launch(void* const* d_in, const int* in_sizes, int n_in,
                              void* d_out, int out_size, void* d_ws, size_t ws_size,
                              hipStream_t stream) {
    const int* ei = (const int*)d_in[1];

    char* ws = (char*)d_ws;
    float* h = (float*)(ws + 0);                            // N*128 f32  (10.24 MB)
    float* pre = (float*)(ws + 10240000);                   // N*128 f32  (10.24 MB)
    unsigned short* qb = (unsigned short*)(ws + 20480000);  // N*512 bf16 (20.48 MB)
    unsigned short* kb = (unsigned short*)(ws + 40960000);
    unsigned short* vb = (unsigned short*)(ws + 61440000);
    float* scoreb = (float*)(ws + 81920000);                // E*4 f32 (2.56 MB)
    int* rowptr = (int*)(ws + 84480000);                    // N+1
    int* cursor = (int*)(ws + 84560128);                    // N
    int* colsrc = (int*)(ws + 84640128);                    // E
    int* flag = (int*)(ws + 85280128);                      // 1 int

    // dtype detection (flag: 0=bf16, 1=f32)
    detect_kernel<<<1, 256, 0, stream>>>((const unsigned short*)d_in[0], flag);

    // CSR build
    hipMemsetAsync(cursor, 0, NNODE * sizeof(int), stream);
    hist_kernel<<<(NEDGE + 255) / 256, 256, 0, stream>>>(ei, cursor);
    scan_kernel<<<1, 1024, 0, stream>>>(cursor, rowptr);
    scatter_kernel<<<(NEDGE + 255) / 256, 256, 0, stream>>>(ei, cursor, colsrc);

    const int GM = (NNODE + 63) / 64; // 313

    // input projection + relu -> h (fp32), dual-dispatch
    gemm_bias<unsigned short, unsigned short, float, true><<<dim3(GM, 2), 256, 0, stream>>>(
        (const unsigned short*)d_in[0], (const unsigned short*)d_in[2],
        (const unsigned short*)d_in[3], h, NNODE, IN_DIMV, HIDV, flag, 0);
    gemm_bias<float, float, float, true><<<dim3(GM, 2), 256, 0, stream>>>(
        (const float*)d_in[0], (const float*)d_in[2],
        (const float*)d_in[3], h, NNODE, IN_DIMV, HIDV, flag, 1);

    for (int l = 0; l < 2; l++) {
        int o = 4 + l * 10;
        // qkv projections (f32 A = h, external W) -> bf16 internal buffers
        unsigned short* outs[3] = {qb, kb, vb};
        for (int t = 0; t < 3; t++) {
            gemm_bias<float, unsigned short, unsigned short, false><<<dim3(GM, 8), 256, 0, stream>>>(
                h, (const unsigned short*)d_in[o + 2 * t], (const unsigned short*)d_in[o + 2 * t + 1],
                outs[t], NNODE, HIDV, H4V, flag, 0);
            gemm_bias<float, float, unsigned short, false><<<dim3(GM, 8), 256, 0, stream>>>(
                h, (const float*)d_in[o + 2 * t], (const float*)d_in[o + 2 * t + 1],
                outs[t], NNODE, HIDV, H4V, flag, 1);
        }
        // skip connection gemm -> pre (f32)
        gemm_bias<float, unsigned short, float, false><<<dim3(GM, 2), 256, 0, stream>>>(
            h, (const unsigned short*)d_in[o + 6], (const unsigned short*)d_in[o + 7],
            pre, NNODE, HIDV, HIDV, flag, 0);
        gemm_bias<float, float, float, false><<<dim3(GM, 2), 256, 0, stream>>>(
            h, (const float*)d_in[o + 6], (const float*)d_in[o + 7],
            pre, NNODE, HIDV, HIDV, flag, 1);

        attn_kernel<<<(NNODE + 3) / 4, 256, 0, stream>>>(
            qb, kb, vb, rowptr, colsrc, scoreb, h, pre);

        void* eo = (l == 1) ? d_out : nullptr;
        ln_kernel<unsigned short><<<(NNODE + 3) / 4, 256, 0, stream>>>(
            pre, (const unsigned short*)d_in[o + 8], (const unsigned short*)d_in[o + 9],
            h, (unsigned short*)eo, flag, 0);
        ln_kernel<float><<<(NNODE + 3) / 4, 256, 0, stream>>>(
            pre, (const float*)d_in[o + 8], (const float*)d_in[o + 9],
            h, (float*)eo, flag, 1);
    }
}

// Round 3
// 426.278 us; speedup vs baseline: 1.9839x; 1.9839x over previous
//
#include <hip/hip_runtime.h>
#include <math.h>

#define NNODE 20000
#define NEDGE 160000
#define IN_DIMV 256
#define HIDV 128
#define NCAT 1664   /* 3*512 QKV + 128 skip */
#define QKV_STRIDE 1536

typedef __attribute__((ext_vector_type(8))) short bf16x8;
typedef __attribute__((ext_vector_type(4))) float f32x4;

__device__ __forceinline__ float bf2f(unsigned short u) {
    union { unsigned int i; float f; } x; x.i = ((unsigned int)u) << 16; return x.f;
}
__device__ __forceinline__ unsigned short f2bf(float f) {
    union { float f; unsigned int i; } x; x.f = f;
    unsigned int r = x.i + 0x7fffu + ((x.i >> 16) & 1u);
    return (unsigned short)(r >> 16);
}
__device__ __forceinline__ void unpack8(uint4 p, float* f) {
    f[0] = bf2f((unsigned short)(p.x & 0xffff)); f[1] = bf2f((unsigned short)(p.x >> 16));
    f[2] = bf2f((unsigned short)(p.y & 0xffff)); f[3] = bf2f((unsigned short)(p.y >> 16));
    f[4] = bf2f((unsigned short)(p.z & 0xffff)); f[5] = bf2f((unsigned short)(p.z >> 16));
    f[6] = bf2f((unsigned short)(p.w & 0xffff)); f[7] = bf2f((unsigned short)(p.w >> 16));
}

// ---------------- weight conversion: f32 W[K,N] -> bf16 WT[N,K] arena ----------------
// arena layout (bf16 elems): [0,32768) inproj WT[128][256];
// then per layer l: 32768 + l*212992 : WT[1664][128] (cols 0..511 q, ..k, ..v, 1536..1663 skip)
__global__ void convert_kernel(
    const float* __restrict__ lin_w,
    const float* __restrict__ qw0, const float* __restrict__ kw0,
    const float* __restrict__ vw0, const float* __restrict__ sw0,
    const float* __restrict__ qw1, const float* __restrict__ kw1,
    const float* __restrict__ vw1, const float* __restrict__ sw1,
    unsigned short* __restrict__ arena)
{
    int idx = blockIdx.x * 256 + threadIdx.x;
    if (idx >= 458752) return;
    float v;
    if (idx < 32768) {
        int n = idx >> 8, k = idx & 255;
        v = lin_w[k * 128 + n];
    } else {
        int t = idx - 32768;
        int l = t / 212992, r = t % 212992;
        int n = r >> 7, k = r & 127;
        const float* qw = l ? qw1 : qw0;
        const float* kw = l ? kw1 : kw0;
        const float* vw = l ? vw1 : vw0;
        const float* sw = l ? sw1 : sw0;
        if (n < 1536) {
            const float* w = (n < 512) ? qw : (n < 1024) ? kw : vw;
            v = w[k * 512 + (n & 511)];
        } else {
            v = sw[k * 128 + (n - 1536)];
        }
    }
    arena[idx] = f2bf(v);
}

// ---------------- MFMA GEMM ----------------
// MODE 0: A = x f32 [M,256] (convert in staging), out = relu(.)+b -> h f32 + hbf bf16, Ncols=128
// MODE 1: A = hbf bf16 [M,128], Ncols=1664: cols<1536 -> qkv bf16 [M,1536]; cols>=1536 -> pre f32 [M,128]
template <int MODE, int K>
__global__ __launch_bounds__(256) void mfma_gemm(
    const void* __restrict__ Av, const unsigned short* __restrict__ WT,
    const float* __restrict__ b0, const float* __restrict__ b1,
    const float* __restrict__ b2, const float* __restrict__ b3,
    unsigned short* __restrict__ qkv_out, float* __restrict__ pre_out,
    float* __restrict__ h_out, unsigned short* __restrict__ hbf_out)
{
    __shared__ unsigned short As[128][40];
    __shared__ unsigned short Bs[128][40];
    int tid = threadIdx.x;
    int lane = tid & 63;
    int wid = tid >> 6;
    int wm = wid & 1, wn = wid >> 1;
    int bm = blockIdx.x * 128;
    int bn = blockIdx.y * 128;

    f32x4 acc[4][4] = {};
    int r0 = tid >> 2, c0 = (tid & 3) * 8;

    for (int k0 = 0; k0 < K; k0 += 32) {
#pragma unroll
        for (int it = 0; it < 2; it++) {
            int r = r0 + it * 64;
            int g = bm + r; if (g > NNODE - 1) g = NNODE - 1;
            if (MODE == 0) {
                const float* A = (const float*)Av;
                const float4* p = (const float4*)(A + (size_t)g * K + k0 + c0);
                float4 u = p[0], w = p[1];
                unsigned short tmp[8] = {f2bf(u.x), f2bf(u.y), f2bf(u.z), f2bf(u.w),
                                         f2bf(w.x), f2bf(w.y), f2bf(w.z), f2bf(w.w)};
                *(uint4*)&As[r][c0] = *(uint4*)tmp;
            } else {
                const unsigned short* A = (const unsigned short*)Av;
                *(uint4*)&As[r][c0] = *(const uint4*)(A + (size_t)g * K + k0 + c0);
            }
            *(uint4*)&Bs[r][c0] = *(const uint4*)(WT + (size_t)(bn + r) * K + k0 + c0);
        }
        __syncthreads();
        bf16x8 fa[4], fb[4];
        int arow = wm * 64 + (lane & 15);
        int brow = wn * 64 + (lane & 15);
        int koff = (lane >> 4) * 8;
#pragma unroll
        for (int i = 0; i < 4; i++) fa[i] = *(const bf16x8*)&As[arow + i * 16][koff];
#pragma unroll
        for (int i = 0; i < 4; i++) fb[i] = *(const bf16x8*)&Bs[brow + i * 16][koff];
#pragma unroll
        for (int mi = 0; mi < 4; mi++)
#pragma unroll
            for (int ni = 0; ni < 4; ni++)
                acc[mi][ni] = __builtin_amdgcn_mfma_f32_16x16x32_bf16(fa[mi], fb[ni], acc[mi][ni], 0, 0, 0);
        __syncthreads();
    }

    int quad = lane >> 4, lcol = lane & 15;
#pragma unroll
    for (int ni = 0; ni < 4; ni++) {
        int col = bn + wn * 64 + ni * 16 + lcol;
        float bias;
        if (MODE == 0) bias = b0[col];
        else bias = (col < 512) ? b0[col]
                  : (col < 1024) ? b1[col - 512]
                  : (col < 1536) ? b2[col - 1024]
                  : b3[col - 1536];
#pragma unroll
        for (int mi = 0; mi < 4; mi++) {
            int rowb = bm + wm * 64 + mi * 16 + quad * 4;
#pragma unroll
            for (int reg = 0; reg < 4; reg++) {
                int row = rowb + reg;
                if (row >= NNODE) continue;
                float v = acc[mi][ni][reg] + bias;
                if (MODE == 0) {
                    v = fmaxf(v, 0.f);
                    h_out[(size_t)row * HIDV + col] = v;
                    hbf_out[(size_t)row * HIDV + col] = f2bf(v);
                } else {
                    if (col < 1536) qkv_out[(size_t)row * QKV_STRIDE + col] = f2bf(v);
                    else pre_out[(size_t)row * HIDV + (col - 1536)] = v;
                }
            }
        }
    }
}

// ---------------- CSR build ----------------
__global__ void hist_kernel(const int* __restrict__ ei, int* __restrict__ counts) {
    int e = blockIdx.x * blockDim.x + threadIdx.x;
    if (e < NEDGE) atomicAdd(&counts[ei[NEDGE + e]], 1);
}

__global__ __launch_bounds__(1024) void scan_kernel(int* __restrict__ cursor,
                                                    int* __restrict__ rowptr) {
    __shared__ int part[1024];
    int tid = threadIdx.x;
    const int CH = 20;
    int base = tid * CH;
    int loc[CH];
    int s = 0;
#pragma unroll
    for (int j = 0; j < CH; j++) {
        int idx = base + j;
        int c = (idx < NNODE) ? cursor[idx] : 0;
        loc[j] = s;
        s += c;
    }
    part[tid] = s;
    __syncthreads();
    for (int off = 1; off < 1024; off <<= 1) {
        int t = (tid >= off) ? part[tid - off] : 0;
        __syncthreads();
        part[tid] += t;
        __syncthreads();
    }
    int offs = part[tid] - s;
#pragma unroll
    for (int j = 0; j < CH; j++) {
        int idx = base + j;
        if (idx < NNODE) {
            int rv = offs + loc[j];
            rowptr[idx] = rv;
            cursor[idx] = rv;
        }
    }
    if (tid == 0) rowptr[NNODE] = NEDGE;
}

__global__ void scatter_kernel(const int* __restrict__ ei, int* __restrict__ cursor,
                               int* __restrict__ colsrc) {
    int e = blockIdx.x * blockDim.x + threadIdx.x;
    if (e < NEDGE) {
        int d = ei[NEDGE + e];
        int p = atomicAdd(&cursor[d], 1);
        colsrc[p] = ei[e];
    }
}

// ---------------- Attention: wave per dst node ----------------
__global__ __launch_bounds__(256) void attn_kernel(
    const unsigned short* __restrict__ qkv, const int* __restrict__ rowptr,
    const int* __restrict__ colsrc, float* __restrict__ scoreb,
    const float* __restrict__ hprev, float* __restrict__ pre)
{
    int lane = threadIdx.x & 63;
    int wid = threadIdx.x >> 6;
    int i = blockIdx.x * 4 + wid;
    if (i >= NNODE) return;
    int rs = rowptr[i], re = rowptr[i + 1];
    int hg = lane >> 4;

    float qr[8];
    {
        uint4 p = *(const uint4*)(qkv + (size_t)i * QKV_STRIDE + lane * 8);
        unpack8(p, qr);
#pragma unroll
        for (int j = 0; j < 8; j++) qr[j] *= 0.0883883476483184f; // 1/sqrt(128)
    }

    float m = -INFINITY, l = 0.f;
    for (int j = rs; j < re; j++) {
        int src = colsrc[j];
        float kf[8];
        uint4 p = *(const uint4*)(qkv + (size_t)src * QKV_STRIDE + 512 + lane * 8);
        unpack8(p, kf);
        float d = qr[0] * kf[0] + qr[1] * kf[1] + qr[2] * kf[2] + qr[3] * kf[3] +
                  qr[4] * kf[4] + qr[5] * kf[5] + qr[6] * kf[6] + qr[7] * kf[7];
        d += __shfl_xor(d, 8);
        d += __shfl_xor(d, 4);
        d += __shfl_xor(d, 2);
        d += __shfl_xor(d, 1);
        if ((lane & 15) == 0) scoreb[(size_t)j * 4 + hg] = d;
        float mn = fmaxf(m, d);
        l = l * __expf(m - mn) + __expf(d - mn);
        m = mn;
    }
    float linv = 1.f / (l + 1e-16f);

    float acc[8] = {0.f, 0.f, 0.f, 0.f, 0.f, 0.f, 0.f, 0.f};
    for (int j = rs; j < re; j++) {
        int src = colsrc[j];
        float cf = __expf(scoreb[(size_t)j * 4 + hg] - m) * linv;
        float vf[8];
        uint4 p = *(const uint4*)(qkv + (size_t)src * QKV_STRIDE + 1024 + lane * 8);
        unpack8(p, vf);
#pragma unroll
        for (int c = 0; c < 8; c++) acc[c] += cf * vf[c];
    }
#pragma unroll
    for (int c = 0; c < 8; c++) {
        acc[c] += __shfl_xor(acc[c], 16);
        acc[c] += __shfl_xor(acc[c], 32);
    }
    if (lane < 16) {
        size_t base = (size_t)i * HIDV + lane * 8;
#pragma unroll
        for (int c = 0; c < 8; c++)
            pre[base + c] = acc[c] * 0.25f + pre[base + c] + hprev[base + c];
    }
}

// ---------------- LayerNorm: wave per node ----------------
__global__ __launch_bounds__(256) void ln_kernel(
    const float* __restrict__ pre, const float* __restrict__ g,
    const float* __restrict__ b, float* __restrict__ hout,
    unsigned short* __restrict__ hbf, float* __restrict__ extout)
{
    int lane = threadIdx.x & 63;
    int wid = threadIdx.x >> 6;
    int i = blockIdx.x * 4 + wid;
    if (i >= NNODE) return;
    float2 xv = ((const float2*)(pre + (size_t)i * HIDV))[lane];
    float s = xv.x + xv.y;
#pragma unroll
    for (int o = 1; o < 64; o <<= 1) s += __shfl_xor(s, o);
    float mu = s * (1.f / 128.f);
    float dx0 = xv.x - mu, dx1 = xv.y - mu;
    float vs = dx0 * dx0 + dx1 * dx1;
#pragma unroll
    for (int o = 1; o < 64; o <<= 1) vs += __shfl_xor(vs, o);
    float rstd = rsqrtf(vs * (1.f / 128.f) + 1e-5f);
    int c0 = lane * 2;
    float y0 = dx0 * rstd * g[c0] + b[c0];
    float y1 = dx1 * rstd * g[c0 + 1] + b[c0 + 1];
    size_t base = (size_t)i * HIDV + c0;
    hout[base] = y0;
    hout[base + 1] = y1;
    hbf[base] = f2bf(y0);
    hbf[base + 1] = f2bf(y1);
    if (extout) {
        extout[base] = y0;
        extout[base + 1] = y1;
    }
}

extern "C" void kernel_launch(void* const* d_in, const int* in_sizes, int n_in,
                              void* d_out, int out_size, void* d_ws, size_t ws_size,
                              hipStream_t stream) {
    const float* x = (const float*)d_in[0];
    const int* ei = (const int*)d_in[1];

    char* ws = (char*)d_ws;
    float* h = (float*)(ws + 0);                              // 20000*128 f32 = 10.24 MB
    unsigned short* hbf = (unsigned short*)(ws + 10240000);   // 20000*128 bf16 = 5.12 MB
    float* pre = (float*)(ws + 15360000);                     // 10.24 MB
    unsigned short* qkv = (unsigned short*)(ws + 25600000);   // 20000*1536 bf16 = 61.44 MB
    float* scoreb = (float*)(ws + 87040000);                  // E*4 f32 = 2.56 MB
    int* rowptr = (int*)(ws + 89600000);                      // N+1
    int* cursor = (int*)(ws + 89680008);                      // N
    int* colsrc = (int*)(ws + 89760008);                      // E
    unsigned short* arena = (unsigned short*)(ws + 90400008); // 458752 bf16 = 0.92 MB

    // weight conversion (f32 -> transposed bf16 arena)
    convert_kernel<<<1792, 256, 0, stream>>>(
        (const float*)d_in[2],
        (const float*)d_in[4], (const float*)d_in[6], (const float*)d_in[8], (const float*)d_in[10],
        (const float*)d_in[14], (const float*)d_in[16], (const float*)d_in[18], (const float*)d_in[20],
        arena);

    // CSR build
    hipMemsetAsync(cursor, 0, NNODE * sizeof(int), stream);
    hist_kernel<<<(NEDGE + 255) / 256, 256, 0, stream>>>(ei, cursor);
    scan_kernel<<<1, 1024, 0, stream>>>(cursor, rowptr);
    scatter_kernel<<<(NEDGE + 255) / 256, 256, 0, stream>>>(ei, cursor, colsrc);

    const int GM = (NNODE + 127) / 128; // 157

    // input projection + relu
    mfma_gemm<0, 256><<<dim3(GM, 1), 256, 0, stream>>>(
        x, arena, (const float*)d_in[3], nullptr, nullptr, nullptr,
        nullptr, nullptr, h, hbf);

    for (int l = 0; l < 2; l++) {
        int o = 4 + l * 10;
        const unsigned short* WT = arena + 32768 + l * 212992;
        mfma_gemm<1, 128><<<dim3(GM, 13), 256, 0, stream>>>(
            hbf, WT,
            (const float*)d_in[o + 1], (const float*)d_in[o + 3],
            (const float*)d_in[o + 5], (const float*)d_in[o + 7],
            qkv, pre, nullptr, nullptr);

        attn_kernel<<<(NNODE + 3) / 4, 256, 0, stream>>>(
            qkv, rowptr, colsrc, scoreb, h, pre);

        ln_kernel<<<(NNODE + 3) / 4, 256, 0, stream>>>(
            pre, (const float*)d_in[o + 8], (const float*)d_in[o + 9],
            h, hbf, (l == 1) ? (float*)d_out : nullptr);
    }
}

// Round 4
// 393.891 us; speedup vs baseline: 2.1470x; 1.0822x over previous
//
#include <hip/hip_runtime.h>
#include <math.h>

#define NNODE 20000
#define NEDGE 160000
#define IN_DIMV 256
#define HIDV 128
#define QKV_STRIDE 1536

typedef __attribute__((ext_vector_type(8))) short bf16x8;
typedef __attribute__((ext_vector_type(4))) float f32x4;

__device__ __forceinline__ float bf2f(unsigned short u) {
    union { unsigned int i; float f; } x; x.i = ((unsigned int)u) << 16; return x.f;
}
__device__ __forceinline__ unsigned short f2bf(float f) {
    union { float f; unsigned int i; } x; x.f = f;
    unsigned int r = x.i + 0x7fffu + ((x.i >> 16) & 1u);
    return (unsigned short)(r >> 16);
}
__device__ __forceinline__ void unpack8(uint4 p, float* f) {
    f[0] = bf2f((unsigned short)(p.x & 0xffff)); f[1] = bf2f((unsigned short)(p.x >> 16));
    f[2] = bf2f((unsigned short)(p.y & 0xffff)); f[3] = bf2f((unsigned short)(p.y >> 16));
    f[4] = bf2f((unsigned short)(p.z & 0xffff)); f[5] = bf2f((unsigned short)(p.z >> 16));
    f[6] = bf2f((unsigned short)(p.w & 0xffff)); f[7] = bf2f((unsigned short)(p.w >> 16));
}

// ---------------- weight conversion: f32 W[K,N] -> bf16 WT[N,K] arena ----------------
__global__ void convert_kernel(
    const float* __restrict__ lin_w,
    const float* __restrict__ qw0, const float* __restrict__ kw0,
    const float* __restrict__ vw0, const float* __restrict__ sw0,
    const float* __restrict__ qw1, const float* __restrict__ kw1,
    const float* __restrict__ vw1, const float* __restrict__ sw1,
    unsigned short* __restrict__ arena)
{
    int idx = blockIdx.x * 256 + threadIdx.x;
    if (idx >= 458752) return;
    float v;
    if (idx < 32768) {
        int n = idx >> 8, k = idx & 255;
        v = lin_w[k * 128 + n];
    } else {
        int t = idx - 32768;
        int l = t / 212992, r = t % 212992;
        int n = r >> 7, k = r & 127;
        const float* qw = l ? qw1 : qw0;
        const float* kw = l ? kw1 : kw0;
        const float* vw = l ? vw1 : vw0;
        const float* sw = l ? sw1 : sw0;
        if (n < 1536) {
            const float* w = (n < 512) ? qw : (n < 1024) ? kw : vw;
            v = w[k * 512 + (n & 511)];
        } else {
            v = sw[k * 128 + (n - 1536)];
        }
    }
    arena[idx] = f2bf(v);
}

// ---------------- MFMA GEMM ----------------
// MODE 0: A = x f32 [M,256] (convert in staging), out = relu(.)+b -> h f32 + hbf bf16, Ncols=128
// MODE 1: A = hbf bf16 [M,128], Ncols=1664: cols<1536 -> qkv bf16; cols>=1536 -> pre f32
template <int MODE, int K>
__global__ __launch_bounds__(256) void mfma_gemm(
    const void* __restrict__ Av, const unsigned short* __restrict__ WT,
    const float* __restrict__ b0, const float* __restrict__ b1,
    const float* __restrict__ b2, const float* __restrict__ b3,
    unsigned short* __restrict__ qkv_out, float* __restrict__ pre_out,
    float* __restrict__ h_out, unsigned short* __restrict__ hbf_out)
{
    __shared__ unsigned short As[128][40];
    __shared__ unsigned short Bs[128][40];
    int tid = threadIdx.x;
    int lane = tid & 63;
    int wid = tid >> 6;
    int wm = wid & 1, wn = wid >> 1;
    int bm = blockIdx.x * 128;
    int bn = blockIdx.y * 128;

    f32x4 acc[4][4] = {};
    int r0 = tid >> 2, c0 = (tid & 3) * 8;

    for (int k0 = 0; k0 < K; k0 += 32) {
#pragma unroll
        for (int it = 0; it < 2; it++) {
            int r = r0 + it * 64;
            int g = bm + r; if (g > NNODE - 1) g = NNODE - 1;
            if (MODE == 0) {
                const float* A = (const float*)Av;
                const float4* p = (const float4*)(A + (size_t)g * K + k0 + c0);
                float4 u = p[0], w = p[1];
                unsigned short tmp[8] = {f2bf(u.x), f2bf(u.y), f2bf(u.z), f2bf(u.w),
                                         f2bf(w.x), f2bf(w.y), f2bf(w.z), f2bf(w.w)};
                *(uint4*)&As[r][c0] = *(uint4*)tmp;
            } else {
                const unsigned short* A = (const unsigned short*)Av;
                *(uint4*)&As[r][c0] = *(const uint4*)(A + (size_t)g * K + k0 + c0);
            }
            *(uint4*)&Bs[r][c0] = *(const uint4*)(WT + (size_t)(bn + r) * K + k0 + c0);
        }
        __syncthreads();
        bf16x8 fa[4], fb[4];
        int arow = wm * 64 + (lane & 15);
        int brow = wn * 64 + (lane & 15);
        int koff = (lane >> 4) * 8;
#pragma unroll
        for (int i = 0; i < 4; i++) fa[i] = *(const bf16x8*)&As[arow + i * 16][koff];
#pragma unroll
        for (int i = 0; i < 4; i++) fb[i] = *(const bf16x8*)&Bs[brow + i * 16][koff];
#pragma unroll
        for (int mi = 0; mi < 4; mi++)
#pragma unroll
            for (int ni = 0; ni < 4; ni++)
                acc[mi][ni] = __builtin_amdgcn_mfma_f32_16x16x32_bf16(fa[mi], fb[ni], acc[mi][ni], 0, 0, 0);
        __syncthreads();
    }

    int quad = lane >> 4, lcol = lane & 15;
#pragma unroll
    for (int ni = 0; ni < 4; ni++) {
        int col = bn + wn * 64 + ni * 16 + lcol;
        float bias;
        if (MODE == 0) bias = b0[col];
        else bias = (col < 512) ? b0[col]
                  : (col < 1024) ? b1[col - 512]
                  : (col < 1536) ? b2[col - 1024]
                  : b3[col - 1536];
#pragma unroll
        for (int mi = 0; mi < 4; mi++) {
            int rowb = bm + wm * 64 + mi * 16 + quad * 4;
#pragma unroll
            for (int reg = 0; reg < 4; reg++) {
                int row = rowb + reg;
                if (row >= NNODE) continue;
                float v = acc[mi][ni][reg] + bias;
                if (MODE == 0) {
                    v = fmaxf(v, 0.f);
                    h_out[(size_t)row * HIDV + col] = v;
                    hbf_out[(size_t)row * HIDV + col] = f2bf(v);
                } else {
                    if (col < 1536) qkv_out[(size_t)row * QKV_STRIDE + col] = f2bf(v);
                    else pre_out[(size_t)row * HIDV + (col - 1536)] = v;
                }
            }
        }
    }
}

// ---------------- CSR build ----------------
__global__ void hist_kernel(const int* __restrict__ ei, int* __restrict__ counts) {
    int e = blockIdx.x * blockDim.x + threadIdx.x;
    if (e < NEDGE) atomicAdd(&counts[ei[NEDGE + e]], 1);
}

__global__ __launch_bounds__(1024) void scan_kernel(int* __restrict__ cursor,
                                                    int* __restrict__ rowptr) {
    __shared__ int part[1024];
    int tid = threadIdx.x;
    const int CH = 20;
    int base = tid * CH;
    int loc[CH];
    int s = 0;
#pragma unroll
    for (int j = 0; j < CH; j++) {
        int idx = base + j;
        int c = (idx < NNODE) ? cursor[idx] : 0;
        loc[j] = s;
        s += c;
    }
    part[tid] = s;
    __syncthreads();
    for (int off = 1; off < 1024; off <<= 1) {
        int t = (tid >= off) ? part[tid - off] : 0;
        __syncthreads();
        part[tid] += t;
        __syncthreads();
    }
    int offs = part[tid] - s;
#pragma unroll
    for (int j = 0; j < CH; j++) {
        int idx = base + j;
        if (idx < NNODE) {
            int rv = offs + loc[j];
            rowptr[idx] = rv;
            cursor[idx] = rv;
        }
    }
    if (tid == 0) rowptr[NNODE] = NEDGE;
}

__global__ void scatter_kernel(const int* __restrict__ ei, int* __restrict__ cursor,
                               int* __restrict__ colsrc) {
    int e = blockIdx.x * blockDim.x + threadIdx.x;
    if (e < NEDGE) {
        int d = ei[NEDGE + e];
        int p = atomicAdd(&cursor[d], 1);
        colsrc[p] = ei[e];
    }
}

// ---------------- Fused attention + residual + LayerNorm: wave per dst node ----------------
// Single-pass online softmax, depth-2 K/V prefetch, LN fused via cross-lane shuffles.
__global__ __launch_bounds__(256) void attn_ln_kernel(
    const unsigned short* __restrict__ qkv, const int* __restrict__ rowptr,
    const int* __restrict__ colsrc, const float* __restrict__ pre,
    const float* __restrict__ g, const float* __restrict__ b,
    float* __restrict__ h /* in: hprev; out: LN result */,
    unsigned short* __restrict__ hbf, float* __restrict__ extout)
{
    int lane = threadIdx.x & 63;
    int wid = threadIdx.x >> 6;
    int i = blockIdx.x * 4 + wid;
    if (i >= NNODE) return;
    int rs = rowptr[i], re = rowptr[i + 1];
    int cnt = re - rs;

    float qr[8];
    {
        uint4 p = *(const uint4*)(qkv + (size_t)i * QKV_STRIDE + lane * 8);
        unpack8(p, qr);
#pragma unroll
        for (int j = 0; j < 8; j++) qr[j] *= 0.0883883476483184f; // 1/sqrt(128)
    }

    float m = -INFINITY, l = 0.f;
    float acc[8] = {0.f, 0.f, 0.f, 0.f, 0.f, 0.f, 0.f, 0.f};

    uint4 k0v, v0v, k1v, v1v;
    if (cnt > 0) {
        const unsigned short* r = qkv + (size_t)colsrc[rs] * QKV_STRIDE + lane * 8;
        k0v = *(const uint4*)(r + 512);
        v0v = *(const uint4*)(r + 1024);
    }
    if (cnt > 1) {
        const unsigned short* r = qkv + (size_t)colsrc[rs + 1] * QKV_STRIDE + lane * 8;
        k1v = *(const uint4*)(r + 512);
        v1v = *(const uint4*)(r + 1024);
    }
    for (int j = 0; j < cnt; j++) {
        uint4 ck = k0v, cv = v0v;
        k0v = k1v; v0v = v1v;
        if (j + 2 < cnt) {
            const unsigned short* r = qkv + (size_t)colsrc[rs + j + 2] * QKV_STRIDE + lane * 8;
            k1v = *(const uint4*)(r + 512);
            v1v = *(const uint4*)(r + 1024);
        }
        float kf[8];
        unpack8(ck, kf);
        float d = qr[0] * kf[0] + qr[1] * kf[1] + qr[2] * kf[2] + qr[3] * kf[3] +
                  qr[4] * kf[4] + qr[5] * kf[5] + qr[6] * kf[6] + qr[7] * kf[7];
        d += __shfl_xor(d, 8);
        d += __shfl_xor(d, 4);
        d += __shfl_xor(d, 2);
        d += __shfl_xor(d, 1);
        float mn = fmaxf(m, d);
        float scale = __expf(m - mn);
        float p = __expf(d - mn);
        l = l * scale + p;
        m = mn;
        float vf[8];
        unpack8(cv, vf);
#pragma unroll
        for (int c = 0; c < 8; c++) acc[c] = acc[c] * scale + p * vf[c];
    }
    float linv = 0.25f / (l + 1e-16f); // per-head normalize x head-mean factor
#pragma unroll
    for (int c = 0; c < 8; c++) acc[c] *= linv;
    // sum across the 4 head groups -> all 64 lanes hold chunk (lane&15)
#pragma unroll
    for (int c = 0; c < 8; c++) {
        acc[c] += __shfl_xor(acc[c], 16);
        acc[c] += __shfl_xor(acc[c], 32);
    }

    // residual: + pre (skip gemm incl. bias) + hprev
    int c16 = lane & 15;
    size_t base = (size_t)i * HIDV + c16 * 8;
    float4 p0 = ((const float4*)(pre + base))[0];
    float4 p1 = ((const float4*)(pre + base))[1];
    float4 h0 = ((const float4*)(h + base))[0];
    float4 h1 = ((const float4*)(h + base))[1];
    float vals[8];
    vals[0] = acc[0] + p0.x + h0.x; vals[1] = acc[1] + p0.y + h0.y;
    vals[2] = acc[2] + p0.z + h0.z; vals[3] = acc[3] + p0.w + h0.w;
    vals[4] = acc[4] + p1.x + h1.x; vals[5] = acc[5] + p1.y + h1.y;
    vals[6] = acc[6] + p1.z + h1.z; vals[7] = acc[7] + p1.w + h1.w;

    // LayerNorm over the 128 values spread across 16 lanes (x4 redundant groups)
    float s = 0.f;
#pragma unroll
    for (int c = 0; c < 8; c++) s += vals[c];
    s += __shfl_xor(s, 1); s += __shfl_xor(s, 2);
    s += __shfl_xor(s, 4); s += __shfl_xor(s, 8);
    float mu = s * (1.f / 128.f);
    float vs = 0.f;
#pragma unroll
    for (int c = 0; c < 8; c++) { float dx = vals[c] - mu; vs += dx * dx; }
    vs += __shfl_xor(vs, 1); vs += __shfl_xor(vs, 2);
    vs += __shfl_xor(vs, 4); vs += __shfl_xor(vs, 8);
    float rstd = rsqrtf(vs * (1.f / 128.f) + 1e-5f);

    float4 g0 = ((const float4*)(g + c16 * 8))[0];
    float4 g1 = ((const float4*)(g + c16 * 8))[1];
    float4 bb0 = ((const float4*)(b + c16 * 8))[0];
    float4 bb1 = ((const float4*)(b + c16 * 8))[1];
    float y[8];
    y[0] = (vals[0] - mu) * rstd * g0.x + bb0.x; y[1] = (vals[1] - mu) * rstd * g0.y + bb0.y;
    y[2] = (vals[2] - mu) * rstd * g0.z + bb0.z; y[3] = (vals[3] - mu) * rstd * g0.w + bb0.w;
    y[4] = (vals[4] - mu) * rstd * g1.x + bb1.x; y[5] = (vals[5] - mu) * rstd * g1.y + bb1.y;
    y[6] = (vals[6] - mu) * rstd * g1.z + bb1.z; y[7] = (vals[7] - mu) * rstd * g1.w + bb1.w;

    if (lane < 16) {
        ((float4*)(h + base))[0] = make_float4(y[0], y[1], y[2], y[3]);
        ((float4*)(h + base))[1] = make_float4(y[4], y[5], y[6], y[7]);
        unsigned short tmp[8] = {f2bf(y[0]), f2bf(y[1]), f2bf(y[2]), f2bf(y[3]),
                                 f2bf(y[4]), f2bf(y[5]), f2bf(y[6]), f2bf(y[7])};
        *(uint4*)(hbf + base) = *(uint4*)tmp;
        if (extout) {
            ((float4*)(extout + base))[0] = make_float4(y[0], y[1], y[2], y[3]);
            ((float4*)(extout + base))[1] = make_float4(y[4], y[5], y[6], y[7]);
        }
    }
}

extern "C" void kernel_launch(void* const* d_in, const int* in_sizes, int n_in,
                              void* d_out, int out_size, void* d_ws, size_t ws_size,
                              hipStream_t stream) {
    const float* x = (const float*)d_in[0];
    const int* ei = (const int*)d_in[1];

    char* ws = (char*)d_ws;
    float* h = (float*)(ws + 0);                              // 10.24 MB
    unsigned short* hbf = (unsigned short*)(ws + 10240000);   // 5.12 MB
    float* pre = (float*)(ws + 15360000);                     // 10.24 MB
    unsigned short* qkv = (unsigned short*)(ws + 25600000);   // 61.44 MB
    int* rowptr = (int*)(ws + 87040000);                      // N+1
    int* cursor = (int*)(ws + 87120008);                      // N
    int* colsrc = (int*)(ws + 87200008);                      // E
    unsigned short* arena = (unsigned short*)(ws + 87840008); // 0.92 MB

    convert_kernel<<<1792, 256, 0, stream>>>(
        (const float*)d_in[2],
        (const float*)d_in[4], (const float*)d_in[6], (const float*)d_in[8], (const float*)d_in[10],
        (const float*)d_in[14], (const float*)d_in[16], (const float*)d_in[18], (const float*)d_in[20],
        arena);

    hipMemsetAsync(cursor, 0, NNODE * sizeof(int), stream);
    hist_kernel<<<(NEDGE + 255) / 256, 256, 0, stream>>>(ei, cursor);
    scan_kernel<<<1, 1024, 0, stream>>>(cursor, rowptr);
    scatter_kernel<<<(NEDGE + 255) / 256, 256, 0, stream>>>(ei, cursor, colsrc);

    const int GM = (NNODE + 127) / 128; // 157

    mfma_gemm<0, 256><<<dim3(GM, 1), 256, 0, stream>>>(
        x, arena, (const float*)d_in[3], nullptr, nullptr, nullptr,
        nullptr, nullptr, h, hbf);

    for (int l = 0; l < 2; l++) {
        int o = 4 + l * 10;
        const unsigned short* WT = arena + 32768 + l * 212992;
        mfma_gemm<1, 128><<<dim3(GM, 13), 256, 0, stream>>>(
            hbf, WT,
            (const float*)d_in[o + 1], (const float*)d_in[o + 3],
            (const float*)d_in[o + 5], (const float*)d_in[o + 7],
            qkv, pre, nullptr, nullptr);

        attn_ln_kernel<<<(NNODE + 3) / 4, 256, 0, stream>>>(
            qkv, rowptr, colsrc, pre,
            (const float*)d_in[o + 8], (const float*)d_in[o + 9],
            h, hbf, (l == 1) ? (float*)d_out : nullptr);
    }
}